// Round 3
// baseline (150.035 us; speedup 1.0000x reference)
//
#include <hip/hip_runtime.h>
#include <stdint.h>

// Problem constants (reference: N=4, L=4096, S=4096, H=8, D=64, fp32 in/out)
#define NB   4
#define LQ   4096
#define SK   4096
#define NHD  8
#define DD   64
#define ROWSTRIDE (NHD * DD)      // 512 floats between consecutive s (or l) rows
#define CH   32                   // S-chunks per (n,h): 4 blocks/CU for k1 TLP
#define SROWS (SK / CH)           // 128 rows per chunk
#define KVSZ (DD * DD)            // 4096
#define PART_STRIDE (KVSZ + DD)   // 4160: KV + Ksum
#define NHTOT (NB * NHD)          // 32
#define LT   64                   // L rows per k3 block
#define EPSF 1e-6f

typedef __attribute__((ext_vector_type(8))) short bf16x8;   // 8 bf16 (4 VGPRs)
typedef __attribute__((ext_vector_type(4))) float f32x4;

union FragU { uint32_t u[4]; bf16x8 v; };

__device__ __forceinline__ float fmap(float x) {
    // elu(x) + 1 == x+1 (x>0) else exp(x)
    return x > 0.f ? x + 1.f : __expf(x);
}

// Truncating hi/lo split of 8 f32 into two bf16x8 fragments.
// hi = trunc_bf16(x); lo = trunc_bf16(x - hi). x ~= hi + lo with rel err ~2^-16.
__device__ __forceinline__ void split8(const float* x, bf16x8& hi, bf16x8& lo) {
    FragU H, L;
#pragma unroll
    for (int p = 0; p < 4; ++p) {
        float a = x[2*p], b = x[2*p+1];
        uint32_t ua = __float_as_uint(a), ub = __float_as_uint(b);
        float ra = a - __uint_as_float(ua & 0xFFFF0000u);   // exact residual
        float rb = b - __uint_as_float(ub & 0xFFFF0000u);
        H.u[p] = (ua >> 16) | (ub & 0xFFFF0000u);
        L.u[p] = (__float_as_uint(ra) >> 16) | (__float_as_uint(rb) & 0xFFFF0000u);
    }
    hi = H.v; lo = L.v;
}

// ---------------------------------------------------------------------------
// k1: partial KV[d][e] = sum_s K~[s][d]*V[s][e]  and  Ksum[d] = sum_s K~[s][d]
// MFMA, no LDS, no barriers. grid: NHTOT*CH = 1024 blocks, 256 threads.
// Single-buffered; __launch_bounds__(256,4) caps VGPR <=128 so the 4
// co-resident blocks/CU actually give 4 waves/SIMD (latency hiding).
// Wave w handles m-tiles {2wm,2wm+1} x n-tiles {2wn,2wn+1} of the 64x64 C.
// Fragment source-k bijection M(i,g) = 16*(i>>2) + 4g + (i&3), identical for
// A and B -> result independent of HW k-layout.
// ---------------------------------------------------------------------------
__global__ __launch_bounds__(256, 4) void k1_kv(const float* __restrict__ Kin,
                                                const float* __restrict__ Vin,
                                                float* __restrict__ part) {
    const int blk   = blockIdx.x;
    const int nh    = blk / CH;
    const int chunk = blk % CH;
    const int n = nh / NHD, h = nh % NHD;
    const int t = threadIdx.x;
    const int w = t >> 6, lane = t & 63;
    const int g = lane >> 4, r = lane & 15;
    const int wm = w & 1, wn = w >> 1;

    const size_t base = ((size_t)n * SK + (size_t)chunk * SROWS) * ROWSTRIDE
                        + (size_t)h * DD;

    const f32x4 zero4 = {0.f, 0.f, 0.f, 0.f};
    f32x4 acc[2][2] = {{zero4, zero4}, {zero4, zero4}};
    float ks[2] = {0.f, 0.f};

    for (int s0 = 0; s0 < SROWS; s0 += 32) {
        float xa[2][8], xb[2][8];
#pragma unroll
        for (int i = 0; i < 8; ++i) {
            const int soff = ((i & 4) << 2) + 4 * g + (i & 3);   // M(i,g)
            const size_t rowb = base + (size_t)(s0 + soff) * ROWSTRIDE;
#pragma unroll
            for (int mt = 0; mt < 2; ++mt)
                xa[mt][i] = Kin[rowb + (wm*2 + mt)*16 + r];
#pragma unroll
            for (int nt = 0; nt < 2; ++nt)
                xb[nt][i] = Vin[rowb + (wn*2 + nt)*16 + r];
        }
        bf16x8 ahi[2], alo[2], bhi[2], blo[2];
#pragma unroll
        for (int mt = 0; mt < 2; ++mt) {
#pragma unroll
            for (int i = 0; i < 8; ++i) xa[mt][i] = fmap(xa[mt][i]);
            if (wn == 0) {          // wave-uniform; avoid double-count (2x dup)
#pragma unroll
                for (int i = 0; i < 8; ++i) ks[mt] += xa[mt][i];
            }
            split8(xa[mt], ahi[mt], alo[mt]);
        }
#pragma unroll
        for (int nt = 0; nt < 2; ++nt) split8(xb[nt], bhi[nt], blo[nt]);
#pragma unroll
        for (int mt = 0; mt < 2; ++mt)
#pragma unroll
            for (int nt = 0; nt < 2; ++nt) {
                acc[mt][nt] = __builtin_amdgcn_mfma_f32_16x16x32_bf16(
                                  ahi[mt], bhi[nt], acc[mt][nt], 0, 0, 0);
                acc[mt][nt] = __builtin_amdgcn_mfma_f32_16x16x32_bf16(
                                  alo[mt], bhi[nt], acc[mt][nt], 0, 0, 0);
                acc[mt][nt] = __builtin_amdgcn_mfma_f32_16x16x32_bf16(
                                  ahi[mt], blo[nt], acc[mt][nt], 0, 0, 0);
            }
    }

    float* pb = part + ((size_t)nh * CH + chunk) * PART_STRIDE;
    // C mapping (m89-verified): col = lane&15, row = 4*(lane>>4) + reg
#pragma unroll
    for (int mt = 0; mt < 2; ++mt) {
        const int dbase = (wm*2 + mt)*16 + 4*g;
#pragma unroll
        for (int nt = 0; nt < 2; ++nt) {
            const int e = (wn*2 + nt)*16 + r;
#pragma unroll
            for (int j = 0; j < 4; ++j)
                pb[(dbase + j) * DD + e] = acc[mt][nt][j];
        }
    }
    if (wn == 0) {
#pragma unroll
        for (int mt = 0; mt < 2; ++mt) {
            float v = ks[mt];
            v += __shfl_xor(v, 16);
            v += __shfl_xor(v, 32);
            if (lane < 16) pb[KVSZ + (wm*2 + mt)*16 + lane] = v;
        }
    }
}

// ---------------------------------------------------------------------------
// k2: sum CH partials -> final [nh][4160]
// ---------------------------------------------------------------------------
__global__ __launch_bounds__(256) void k2_reduce(const float* __restrict__ part,
                                                 float* __restrict__ fin) {
    const int idx = blockIdx.x * 256 + threadIdx.x;
    if (idx >= NHTOT * PART_STRIDE) return;
    const int nh = idx / PART_STRIDE;
    const int j  = idx - nh * PART_STRIDE;
    const float* p = part + (size_t)nh * CH * PART_STRIDE + j;
    float s = 0.f;
#pragma unroll
    for (int cix = 0; cix < CH; ++cix) s += p[(size_t)cix * PART_STRIDE];
    fin[idx] = s;
}

// ---------------------------------------------------------------------------
// k3: out[l][e] = (sum_d Q~[l][d]*KV[d][e]) / (sum_d Q~[l][d]*Ksum[d] + eps)
// MFMA. KV staged once per block into LDS as pre-split bf16 hi/lo, transposed
// to [e][k'] with column permutation k'(d) s.t. each B fragment is one aligned
// ds_read_b128, plus (e&3)<<3 XOR swizzle. z stays fully fp32.
// grid: NHTOT*64 blocks, 256 threads (round-1 shape: full 32 waves/CU).
// Staging uses float4 loads (4 per thread) — round 2's improvement kept.
// ---------------------------------------------------------------------------
#define KVSTR 72   // bf16 row stride: 144 B, keeps b128 reads aligned

__global__ __launch_bounds__(256) void k3_out(const float* __restrict__ Qin,
                                              const float* __restrict__ fin,
                                              float* __restrict__ out) {
    const int blk = blockIdx.x;
    const int nh  = blk >> 6;        // 64 L-chunks per nh
    const int lc  = blk & 63;
    const int n = nh >> 3, h = nh & 7;
    const int t = threadIdx.x;
    const int w = t >> 6, lane = t & 63;
    const int g = lane >> 4, r = lane & 15;

    __shared__ __align__(16) short KThi[DD][KVSTR];
    __shared__ __align__(16) short KTlo[DD][KVSTR];
    __shared__ __align__(16) float Ksm[DD];

    const float* fb = fin + (size_t)nh * PART_STRIDE;
    {
        // stage: thread t handles flat elements 16t..16t+15 (d = t>>2 const,
        // e = 16*(t&3) + m) -> four float4 loads, fully coalesced
        const int i0 = t * 16;
        const int d  = i0 >> 6;          // t>>2
        const int e0 = i0 & 63;          // (t&3)*16
        float xs[16];
#pragma unroll
        for (int q = 0; q < 4; ++q) {
            const float4 x4 = *(const float4*)(fb + i0 + 4*q);
            xs[4*q+0] = x4.x; xs[4*q+1] = x4.y; xs[4*q+2] = x4.z; xs[4*q+3] = x4.w;
        }
        // k'(d): bits [d5][d3 d2][d4][d1 d0] (bijection)
        const int colb = (d & 32) | (d & 3) | (((d >> 4) & 1) << 2)
                         | (((d >> 2) & 3) << 3);
#pragma unroll
        for (int m = 0; m < 16; ++m) {
            const int e = e0 + m;
            const int col = colb ^ ((e & 3) << 3);
            const float x = xs[m];
            const uint32_t ux = __float_as_uint(x);
            const float lo = x - __uint_as_float(ux & 0xFFFF0000u);
            KThi[e][col] = (short)(ux >> 16);
            KTlo[e][col] = (short)(__float_as_uint(lo) >> 16);
        }
        if (t < DD) Ksm[t] = fb[KVSZ + t];
    }
    __syncthreads();

    const size_t qrow = (size_t)n * LQ + (size_t)lc * LT + w * 16 + r;
    const float* qp = Qin + qrow * ROWSTRIDE + (size_t)h * DD;

    const f32x4 zero4 = {0.f, 0.f, 0.f, 0.f};
    f32x4 acc[4] = {zero4, zero4, zero4, zero4};
    float z = 0.f;

#pragma unroll
    for (int kst = 0; kst < 2; ++kst) {
        const int kb = kst * 32;
        // A fragment: Q row r of this wave's tile, k = kb + M(i,g) — contiguous
        const float4 qa = *(const float4*)(qp + kb + 4*g);
        const float4 qb = *(const float4*)(qp + kb + 16 + 4*g);
        float qv[8] = {fmap(qa.x), fmap(qa.y), fmap(qa.z), fmap(qa.w),
                       fmap(qb.x), fmap(qb.y), fmap(qb.z), fmap(qb.w)};
        // z partial in full fp32 against fp32 Ksum (same k indices)
        const float4 ka = *(const float4*)&Ksm[kb + 4*g];
        const float4 kc = *(const float4*)&Ksm[kb + 16 + 4*g];
        z += qv[0]*ka.x + qv[1]*ka.y + qv[2]*ka.z + qv[3]*ka.w
           + qv[4]*kc.x + qv[5]*kc.y + qv[6]*kc.z + qv[7]*kc.w;
        bf16x8 ahi, alo;
        split8(qv, ahi, alo);
        const int cswz = 8 * (g ^ (r & 3));   // undo staging swizzle (e&3 == r&3)
#pragma unroll
        for (int nt = 0; nt < 4; ++nt) {
            const int e = nt*16 + r;
            const bf16x8 bh = *(const bf16x8*)&KThi[e][kb + cswz];
            const bf16x8 bl = *(const bf16x8*)&KTlo[e][kb + cswz];
            acc[nt] = __builtin_amdgcn_mfma_f32_16x16x32_bf16(ahi, bh, acc[nt], 0,0,0);
            acc[nt] = __builtin_amdgcn_mfma_f32_16x16x32_bf16(alo, bh, acc[nt], 0,0,0);
            acc[nt] = __builtin_amdgcn_mfma_f32_16x16x32_bf16(ahi, bl, acc[nt], 0,0,0);
        }
    }

    // z: sum over g-groups -> every lane holds full z for its A-row r
    z += __shfl_xor(z, 16);
    z += __shfl_xor(z, 32);

    const size_t obase0 = ((size_t)n * LQ + (size_t)lc * LT + w * 16) * ROWSTRIDE
                          + (size_t)h * DD;
#pragma unroll
    for (int j = 0; j < 4; ++j) {
        // C row = 4g + j; its z lives in lane (4g+j) (lanes 0..15 hold r==lane)
        const float zj = __shfl(z, 4*g + j);
        const float zi = 1.f / (zj + EPSF);
        const size_t ob = obase0 + (size_t)(4*g + j) * ROWSTRIDE;
#pragma unroll
        for (int nt = 0; nt < 4; ++nt)
            out[ob + nt*16 + r] = acc[nt][j] * zi;
    }
}

// ---------------------------------------------------------------------------
extern "C" void kernel_launch(void* const* d_in, const int* in_sizes, int n_in,
                              void* d_out, int out_size, void* d_ws, size_t ws_size,
                              hipStream_t stream) {
    const float* Q = (const float*)d_in[0];
    const float* K = (const float*)d_in[1];
    const float* V = (const float*)d_in[2];
    float* out = (float*)d_out;

    float* ws   = (float*)d_ws;
    float* part = ws;                                        // 1024*4160 floats (~17 MB)
    float* fin  = ws + (size_t)NHTOT * CH * PART_STRIDE;     // 32*4160 floats

    k1_kv<<<NHTOT * CH, 256, 0, stream>>>(K, V, part);
    k2_reduce<<<(NHTOT * PART_STRIDE + 255) / 256, 256, 0, stream>>>(part, fin);
    k3_out<<<NHTOT * (LQ / LT), 256, 0, stream>>>(Q, fin, out);
}

// Round 4
// 146.206 us; speedup vs baseline: 1.0262x; 1.0262x over previous
//
#include <hip/hip_runtime.h>
#include <stdint.h>

// Problem constants (reference: N=4, L=4096, S=4096, H=8, D=64, fp32 in/out)
#define NB   4
#define LQ   4096
#define SK   4096
#define NHD  8
#define DD   64
#define ROWSTRIDE (NHD * DD)      // 512 floats between consecutive s (or l) rows
#define CH   16                   // S-chunks per (n,h)  (R1 champion value)
#define SROWS (SK / CH)           // 256 rows per chunk
#define KVSZ (DD * DD)            // 4096
#define PART_STRIDE (KVSZ + DD)   // 4160: KV + Ksum
#define NHTOT (NB * NHD)          // 32
#define LT   64                   // L rows per k3 block
#define EPSF 1e-6f
#define FINSZ (NHTOT * PART_STRIDE)   // 133120 floats

typedef __attribute__((ext_vector_type(8))) short bf16x8;   // 8 bf16 (4 VGPRs)
typedef __attribute__((ext_vector_type(4))) float f32x4;

union FragU { uint32_t u[4]; bf16x8 v; };

__device__ __forceinline__ float fmap(float x) {
    // elu(x) + 1 == x+1 (x>0) else exp(x)
    return x > 0.f ? x + 1.f : __expf(x);
}

// Truncating hi/lo split of 8 f32 into two bf16x8 fragments.
// hi = trunc_bf16(x); lo = trunc_bf16(x - hi). x ~= hi + lo with rel err ~2^-16.
__device__ __forceinline__ void split8(const float* x, bf16x8& hi, bf16x8& lo) {
    FragU H, L;
#pragma unroll
    for (int p = 0; p < 4; ++p) {
        float a = x[2*p], b = x[2*p+1];
        uint32_t ua = __float_as_uint(a), ub = __float_as_uint(b);
        float ra = a - __uint_as_float(ua & 0xFFFF0000u);   // exact residual
        float rb = b - __uint_as_float(ub & 0xFFFF0000u);
        H.u[p] = (ua >> 16) | (ub & 0xFFFF0000u);
        L.u[p] = (__float_as_uint(ra) >> 16) | (__float_as_uint(rb) & 0xFFFF0000u);
    }
    hi = H.v; lo = L.v;
}

// ---------------------------------------------------------------------------
// z0: zero fin (533 KB) so k1 can accumulate with atomics.
// ---------------------------------------------------------------------------
__global__ __launch_bounds__(256) void z0_zero(float* __restrict__ fin) {
    const int i = (blockIdx.x * 256 + threadIdx.x) * 4;
    if (i < FINSZ) {
        *(float4*)(fin + i) = make_float4(0.f, 0.f, 0.f, 0.f);
    }
}

// ---------------------------------------------------------------------------
// k1: fin[nh] += KV[d][e] = sum_s K~[s][d]*V[s][e]  and  Ksum[d] += ...
// MFMA, no LDS, no barriers. grid: NHTOT*CH = 512 blocks, 256 threads.
// Single-buffered, natural occupancy (no forced launch-bounds min).
// Wave w handles m-tiles {2wm,2wm+1} x n-tiles {2wn,2wn+1} of the 64x64 C.
// Fragment source-k bijection M(i,g) = 16*(i>>2) + 4g + (i&3), identical for
// A and B -> result independent of HW k-layout.
// Chunk partials accumulate into fin via device-scope atomicAdd (16 writers
// per address over kernel lifetime -> negligible contention); removes the
// 17 MB part round-trip and the k2 launch entirely.
// ---------------------------------------------------------------------------
__global__ __launch_bounds__(256) void k1_kv(const float* __restrict__ Kin,
                                             const float* __restrict__ Vin,
                                             float* __restrict__ fin) {
    const int blk   = blockIdx.x;
    const int nh    = blk / CH;
    const int chunk = blk % CH;
    const int n = nh / NHD, h = nh % NHD;
    const int t = threadIdx.x;
    const int w = t >> 6, lane = t & 63;
    const int g = lane >> 4, r = lane & 15;
    const int wm = w & 1, wn = w >> 1;

    const size_t base = ((size_t)n * SK + (size_t)chunk * SROWS) * ROWSTRIDE
                        + (size_t)h * DD;

    const f32x4 zero4 = {0.f, 0.f, 0.f, 0.f};
    f32x4 acc[2][2] = {{zero4, zero4}, {zero4, zero4}};
    float ks[2] = {0.f, 0.f};

    for (int s0 = 0; s0 < SROWS; s0 += 32) {
        float xa[2][8], xb[2][8];
#pragma unroll
        for (int i = 0; i < 8; ++i) {
            const int soff = ((i & 4) << 2) + 4 * g + (i & 3);   // M(i,g)
            const size_t rowb = base + (size_t)(s0 + soff) * ROWSTRIDE;
#pragma unroll
            for (int mt = 0; mt < 2; ++mt)
                xa[mt][i] = Kin[rowb + (wm*2 + mt)*16 + r];
#pragma unroll
            for (int nt = 0; nt < 2; ++nt)
                xb[nt][i] = Vin[rowb + (wn*2 + nt)*16 + r];
        }
        bf16x8 ahi[2], alo[2], bhi[2], blo[2];
#pragma unroll
        for (int mt = 0; mt < 2; ++mt) {
#pragma unroll
            for (int i = 0; i < 8; ++i) xa[mt][i] = fmap(xa[mt][i]);
            if (wn == 0) {          // wave-uniform; avoid double-count (2x dup)
#pragma unroll
                for (int i = 0; i < 8; ++i) ks[mt] += xa[mt][i];
            }
            split8(xa[mt], ahi[mt], alo[mt]);
        }
#pragma unroll
        for (int nt = 0; nt < 2; ++nt) split8(xb[nt], bhi[nt], blo[nt]);
#pragma unroll
        for (int mt = 0; mt < 2; ++mt)
#pragma unroll
            for (int nt = 0; nt < 2; ++nt) {
                acc[mt][nt] = __builtin_amdgcn_mfma_f32_16x16x32_bf16(
                                  ahi[mt], bhi[nt], acc[mt][nt], 0, 0, 0);
                acc[mt][nt] = __builtin_amdgcn_mfma_f32_16x16x32_bf16(
                                  alo[mt], bhi[nt], acc[mt][nt], 0, 0, 0);
                acc[mt][nt] = __builtin_amdgcn_mfma_f32_16x16x32_bf16(
                                  ahi[mt], blo[nt], acc[mt][nt], 0, 0, 0);
            }
    }

    float* pb = fin + (size_t)nh * PART_STRIDE;
    // C mapping (m89-verified): col = lane&15, row = 4*(lane>>4) + reg
#pragma unroll
    for (int mt = 0; mt < 2; ++mt) {
        const int dbase = (wm*2 + mt)*16 + 4*g;
#pragma unroll
        for (int nt = 0; nt < 2; ++nt) {
            const int e = (wn*2 + nt)*16 + r;
#pragma unroll
            for (int j = 0; j < 4; ++j)
                atomicAdd(pb + (dbase + j) * DD + e, acc[mt][nt][j]);
        }
    }
    if (wn == 0) {
#pragma unroll
        for (int mt = 0; mt < 2; ++mt) {
            float v = ks[mt];
            v += __shfl_xor(v, 16);
            v += __shfl_xor(v, 32);
            if (lane < 16) atomicAdd(pb + KVSZ + (wm*2 + mt)*16 + lane, v);
        }
    }
}

// ---------------------------------------------------------------------------
// k3: out[l][e] = (sum_d Q~[l][d]*KV[d][e]) / (sum_d Q~[l][d]*Ksum[d] + eps)
// MFMA. KV staged once per block into LDS as pre-split bf16 hi/lo, transposed
// to [e][k'] with column permutation k'(d) s.t. each B fragment is one aligned
// ds_read_b128, plus (e&3)<<3 XOR swizzle. z stays fully fp32.
// grid: NHTOT*64 blocks, 256 threads (R1 shape: full 32 waves/CU).
// Staging uses float4 loads (4 per thread).
// ---------------------------------------------------------------------------
#define KVSTR 72   // bf16 row stride: 144 B, keeps b128 reads aligned

__global__ __launch_bounds__(256) void k3_out(const float* __restrict__ Qin,
                                              const float* __restrict__ fin,
                                              float* __restrict__ out) {
    const int blk = blockIdx.x;
    const int nh  = blk >> 6;        // 64 L-chunks per nh
    const int lc  = blk & 63;
    const int n = nh >> 3, h = nh & 7;
    const int t = threadIdx.x;
    const int w = t >> 6, lane = t & 63;
    const int g = lane >> 4, r = lane & 15;

    __shared__ __align__(16) short KThi[DD][KVSTR];
    __shared__ __align__(16) short KTlo[DD][KVSTR];
    __shared__ __align__(16) float Ksm[DD];

    const float* fb = fin + (size_t)nh * PART_STRIDE;
    {
        // stage: thread t handles flat elements 16t..16t+15 (d = t>>2 const,
        // e = 16*(t&3) + m) -> four float4 loads, fully coalesced
        const int i0 = t * 16;
        const int d  = i0 >> 6;          // t>>2
        const int e0 = i0 & 63;          // (t&3)*16
        float xs[16];
#pragma unroll
        for (int q = 0; q < 4; ++q) {
            const float4 x4 = *(const float4*)(fb + i0 + 4*q);
            xs[4*q+0] = x4.x; xs[4*q+1] = x4.y; xs[4*q+2] = x4.z; xs[4*q+3] = x4.w;
        }
        // k'(d): bits [d5][d3 d2][d4][d1 d0] (bijection)
        const int colb = (d & 32) | (d & 3) | (((d >> 4) & 1) << 2)
                         | (((d >> 2) & 3) << 3);
#pragma unroll
        for (int m = 0; m < 16; ++m) {
            const int e = e0 + m;
            const int col = colb ^ ((e & 3) << 3);
            const float x = xs[m];
            const uint32_t ux = __float_as_uint(x);
            const float lo = x - __uint_as_float(ux & 0xFFFF0000u);
            KThi[e][col] = (short)(ux >> 16);
            KTlo[e][col] = (short)(__float_as_uint(lo) >> 16);
        }
        if (t < DD) Ksm[t] = fb[KVSZ + t];
    }
    __syncthreads();

    const size_t qrow = (size_t)n * LQ + (size_t)lc * LT + w * 16 + r;
    const float* qp = Qin + qrow * ROWSTRIDE + (size_t)h * DD;

    const f32x4 zero4 = {0.f, 0.f, 0.f, 0.f};
    f32x4 acc[4] = {zero4, zero4, zero4, zero4};
    float z = 0.f;

#pragma unroll
    for (int kst = 0; kst < 2; ++kst) {
        const int kb = kst * 32;
        // A fragment: Q row r of this wave's tile, k = kb + M(i,g) — contiguous
        const float4 qa = *(const float4*)(qp + kb + 4*g);
        const float4 qb = *(const float4*)(qp + kb + 16 + 4*g);
        float qv[8] = {fmap(qa.x), fmap(qa.y), fmap(qa.z), fmap(qa.w),
                       fmap(qb.x), fmap(qb.y), fmap(qb.z), fmap(qb.w)};
        // z partial in full fp32 against fp32 Ksum (same k indices)
        const float4 ka = *(const float4*)&Ksm[kb + 4*g];
        const float4 kc = *(const float4*)&Ksm[kb + 16 + 4*g];
        z += qv[0]*ka.x + qv[1]*ka.y + qv[2]*ka.z + qv[3]*ka.w
           + qv[4]*kc.x + qv[5]*kc.y + qv[6]*kc.z + qv[7]*kc.w;
        bf16x8 ahi, alo;
        split8(qv, ahi, alo);
        const int cswz = 8 * (g ^ (r & 3));   // undo staging swizzle (e&3 == r&3)
#pragma unroll
        for (int nt = 0; nt < 4; ++nt) {
            const int e = nt*16 + r;
            const bf16x8 bh = *(const bf16x8*)&KThi[e][kb + cswz];
            const bf16x8 bl = *(const bf16x8*)&KTlo[e][kb + cswz];
            acc[nt] = __builtin_amdgcn_mfma_f32_16x16x32_bf16(ahi, bh, acc[nt], 0,0,0);
            acc[nt] = __builtin_amdgcn_mfma_f32_16x16x32_bf16(alo, bh, acc[nt], 0,0,0);
            acc[nt] = __builtin_amdgcn_mfma_f32_16x16x32_bf16(ahi, bl, acc[nt], 0,0,0);
        }
    }

    // z: sum over g-groups -> every lane holds full z for its A-row r
    z += __shfl_xor(z, 16);
    z += __shfl_xor(z, 32);

    const size_t obase0 = ((size_t)n * LQ + (size_t)lc * LT + w * 16) * ROWSTRIDE
                          + (size_t)h * DD;
#pragma unroll
    for (int j = 0; j < 4; ++j) {
        // C row = 4g + j; its z lives in lane (4g+j) (lanes 0..15 hold r==lane)
        const float zj = __shfl(z, 4*g + j);
        const float zi = 1.f / (zj + EPSF);
        const size_t ob = obase0 + (size_t)(4*g + j) * ROWSTRIDE;
#pragma unroll
        for (int nt = 0; nt < 4; ++nt)
            out[ob + nt*16 + r] = acc[nt][j] * zi;
    }
}

// ---------------------------------------------------------------------------
extern "C" void kernel_launch(void* const* d_in, const int* in_sizes, int n_in,
                              void* d_out, int out_size, void* d_ws, size_t ws_size,
                              hipStream_t stream) {
    const float* Q = (const float*)d_in[0];
    const float* K = (const float*)d_in[1];
    const float* V = (const float*)d_in[2];
    float* out = (float*)d_out;

    float* fin = (float*)d_ws;    // 133120 floats (~533 KB), zeroed by z0

    z0_zero<<<(FINSZ / 4 + 255) / 256, 256, 0, stream>>>(fin);
    k1_kv<<<NHTOT * CH, 256, 0, stream>>>(K, V, fin);
    k3_out<<<NHTOT * (LQ / LT), 256, 0, stream>>>(Q, fin, out);
}

// Round 5
// 144.935 us; speedup vs baseline: 1.0352x; 1.0088x over previous
//
#include <hip/hip_runtime.h>
#include <stdint.h>

// Problem constants (reference: N=4, L=4096, S=4096, H=8, D=64, fp32 in/out)
#define NB   4
#define LQ   4096
#define SK   4096
#define NHD  8
#define DD   64
#define ROWSTRIDE (NHD * DD)      // 512 floats between consecutive s (or l) rows
#define CH   16                   // S-chunks per (n,h)  (R1 champion value)
#define SROWS (SK / CH)           // 256 rows per chunk
#define KVSZ (DD * DD)            // 4096
#define PART_STRIDE (KVSZ + DD)   // 4160: KV + Ksum
#define NHTOT (NB * NHD)          // 32
#define LT   64                   // L rows per k3 block
#define EPSF 1e-6f

typedef __attribute__((ext_vector_type(8))) short bf16x8;   // 8 bf16 (4 VGPRs)
typedef __attribute__((ext_vector_type(4))) float f32x4;

union FragU  { uint32_t u[4]; bf16x8 v; };
union Frag128 { uint4 q; bf16x8 v; };

__device__ __forceinline__ float fmap(float x) {
    // elu(x) + 1 == x+1 (x>0) else exp(x)
    return x > 0.f ? x + 1.f : __expf(x);
}

// Truncating hi/lo split of 8 f32 into two bf16x8 fragments (register path, k3).
__device__ __forceinline__ void split8(const float* x, bf16x8& hi, bf16x8& lo) {
    FragU H, L;
#pragma unroll
    for (int p = 0; p < 4; ++p) {
        float a = x[2*p], b = x[2*p+1];
        uint32_t ua = __float_as_uint(a), ub = __float_as_uint(b);
        float ra = a - __uint_as_float(ua & 0xFFFF0000u);   // exact residual
        float rb = b - __uint_as_float(ub & 0xFFFF0000u);
        H.u[p] = (ua >> 16) | (ub & 0xFFFF0000u);
        L.u[p] = (__float_as_uint(ra) >> 16) | (__float_as_uint(rb) & 0xFFFF0000u);
    }
    hi = H.v; lo = L.v;
}

// Split one f32 pair (a = even-s, b = odd-s) into packed hi/lo u32 words.
__device__ __forceinline__ void split_pair(float a, float b,
                                           uint32_t& hi, uint32_t& lo) {
    uint32_t ua = __float_as_uint(a), ub = __float_as_uint(b);
    float ra = a - __uint_as_float(ua & 0xFFFF0000u);
    float rb = b - __uint_as_float(ub & 0xFFFF0000u);
    hi = (ua >> 16) | (ub & 0xFFFF0000u);
    lo = (__float_as_uint(ra) >> 16) | (__float_as_uint(rb) & 0xFFFF0000u);
}

// ---------------------------------------------------------------------------
// k1: partial KV[d][e] = sum_s K~[s][d]*V[s][e]  and  Ksum[d] = sum_s K~[s][d]
// grid: NHTOT*CH = 512 blocks, 256 threads (4 waves).
// Canonical staged-GEMM form: coalesced float4 global loads (1 KB/wave/instr),
// fmap+bf16 hi/lo split ONCE at staging, packed u32 planes [d][s/2] in LDS;
// each MFMA fragment = one aligned ds_read_b128. Register-pipelined: tile t+1
// loads issue before tile t compute. k-bijection M'(i,g) = 8g+i on BOTH A and
// B sides -> result independent of HW k-layout.
// Ksum accumulated at staging (each element staged exactly once), 16-lane
// shfl reduce, no LDS round-trip.
// ---------------------------------------------------------------------------
#define PWORDS 20   // u32 words per plane row (16 used + 4 pad); 80 B row stride

__global__ __launch_bounds__(256) void k1_kv(const float* __restrict__ Kin,
                                             const float* __restrict__ Vin,
                                             float* __restrict__ part) {
    const int blk   = blockIdx.x;
    const int nh    = blk / CH;
    const int chunk = blk % CH;
    const int n = nh / NHD, h = nh % NHD;
    const int t = threadIdx.x;
    const int w = t >> 6, lane = t & 63;
    const int g = lane >> 4, r = lane & 15;
    const int wm = w & 1, wn = w >> 1;

    // staging coords: thread covers rows {2*sp, 2*sp+1} of the 32-row tile,
    // cols 4*c4 .. 4*c4+3
    const int sp = t & 15;          // s-pair index 0..15
    const int c4 = t >> 4;          // col-quad 0..15

    __shared__ __align__(16) uint32_t KHi[DD][PWORDS];
    __shared__ __align__(16) uint32_t KLo[DD][PWORDS];
    __shared__ __align__(16) uint32_t VHi[DD][PWORDS];
    __shared__ __align__(16) uint32_t VLo[DD][PWORDS];

    const size_t base = ((size_t)n * SK + (size_t)chunk * SROWS) * ROWSTRIDE
                        + (size_t)h * DD;
    const float* kp = Kin + base + (size_t)(2 * sp) * ROWSTRIDE + 4 * c4;
    const float* vp = Vin + base + (size_t)(2 * sp) * ROWSTRIDE + 4 * c4;

    const f32x4 zero4 = {0.f, 0.f, 0.f, 0.f};
    f32x4 acc[2][2] = {{zero4, zero4}, {zero4, zero4}};
    float ks[4] = {0.f, 0.f, 0.f, 0.f};

    float4 k0 = *(const float4*)(kp);
    float4 k1 = *(const float4*)(kp + ROWSTRIDE);
    float4 v0 = *(const float4*)(vp);
    float4 v1 = *(const float4*)(vp + ROWSTRIDE);

#pragma unroll
    for (int tile = 0; tile < SROWS / 32; ++tile) {
        if (tile > 0) __syncthreads();   // prior tile's LDS reads complete

        // ---- stage current regs -> LDS (fmap K, split both, pack s-pairs)
        {
            float kf0[4] = {fmap(k0.x), fmap(k0.y), fmap(k0.z), fmap(k0.w)};
            float kf1[4] = {fmap(k1.x), fmap(k1.y), fmap(k1.z), fmap(k1.w)};
            float vv0[4] = {v0.x, v0.y, v0.z, v0.w};
            float vv1[4] = {v1.x, v1.y, v1.z, v1.w};
#pragma unroll
            for (int q = 0; q < 4; ++q) {
                ks[q] += kf0[q] + kf1[q];
                const int d = 4 * c4 + q;
                uint32_t hi, lo;
                split_pair(kf0[q], kf1[q], hi, lo);
                KHi[d][sp] = hi; KLo[d][sp] = lo;
                split_pair(vv0[q], vv1[q], hi, lo);
                VHi[d][sp] = hi; VLo[d][sp] = lo;
            }
        }
        __syncthreads();

        // ---- issue next tile's loads (overlap with compute below)
        if (tile < SROWS / 32 - 1) {
            const size_t adv = (size_t)(tile + 1) * 32 * ROWSTRIDE;
            k0 = *(const float4*)(kp + adv);
            k1 = *(const float4*)(kp + adv + ROWSTRIDE);
            v0 = *(const float4*)(vp + adv);
            v1 = *(const float4*)(vp + adv + ROWSTRIDE);
        }

        // ---- MFMA K-step over the 32 staged rows
        // A fragment element j <-> s = 8g + j  (M'(j,g), same on B side)
        Frag128 ahi[2], alo[2], bhi[2], blo[2];
#pragma unroll
        for (int mt = 0; mt < 2; ++mt) {
            const int d = (wm * 2 + mt) * 16 + r;
            ahi[mt].q = *(const uint4*)&KHi[d][4 * g];
            alo[mt].q = *(const uint4*)&KLo[d][4 * g];
        }
#pragma unroll
        for (int nt = 0; nt < 2; ++nt) {
            const int e = (wn * 2 + nt) * 16 + r;
            bhi[nt].q = *(const uint4*)&VHi[e][4 * g];
            blo[nt].q = *(const uint4*)&VLo[e][4 * g];
        }
#pragma unroll
        for (int mt = 0; mt < 2; ++mt)
#pragma unroll
            for (int nt = 0; nt < 2; ++nt) {
                acc[mt][nt] = __builtin_amdgcn_mfma_f32_16x16x32_bf16(
                                  ahi[mt].v, bhi[nt].v, acc[mt][nt], 0, 0, 0);
                acc[mt][nt] = __builtin_amdgcn_mfma_f32_16x16x32_bf16(
                                  alo[mt].v, bhi[nt].v, acc[mt][nt], 0, 0, 0);
                acc[mt][nt] = __builtin_amdgcn_mfma_f32_16x16x32_bf16(
                                  ahi[mt].v, blo[nt].v, acc[mt][nt], 0, 0, 0);
            }
    }

    float* pb = part + ((size_t)nh * CH + chunk) * PART_STRIDE;
    // C mapping (m89-verified): col = lane&15, row = 4*(lane>>4) + reg
#pragma unroll
    for (int mt = 0; mt < 2; ++mt) {
        const int dbase = (wm * 2 + mt) * 16 + 4 * g;
#pragma unroll
        for (int nt = 0; nt < 2; ++nt) {
            const int e = (wn * 2 + nt) * 16 + r;
#pragma unroll
            for (int j = 0; j < 4; ++j)
                pb[(dbase + j) * DD + e] = acc[mt][nt][j];
        }
    }

    // Ksum: reduce ks[4] over the 16 sp-lanes of each c4 group (within-wave)
#pragma unroll
    for (int m = 1; m < 16; m <<= 1) {
#pragma unroll
        for (int q = 0; q < 4; ++q) ks[q] += __shfl_xor(ks[q], m);
    }
    if (sp == 0) {
        *(float4*)(pb + KVSZ + 4 * c4) = make_float4(ks[0], ks[1], ks[2], ks[3]);
    }
}

// ---------------------------------------------------------------------------
// k2: sum CH partials -> final [nh][4160]
// ---------------------------------------------------------------------------
__global__ __launch_bounds__(256) void k2_reduce(const float* __restrict__ part,
                                                 float* __restrict__ fin) {
    const int idx = blockIdx.x * 256 + threadIdx.x;
    if (idx >= NHTOT * PART_STRIDE) return;
    const int nh = idx / PART_STRIDE;
    const int j  = idx - nh * PART_STRIDE;
    const float* p = part + (size_t)nh * CH * PART_STRIDE + j;
    float s = 0.f;
#pragma unroll
    for (int cix = 0; cix < CH; ++cix) s += p[(size_t)cix * PART_STRIDE];
    fin[idx] = s;
}

// ---------------------------------------------------------------------------
// k3: out[l][e] = (sum_d Q~[l][d]*KV[d][e]) / (sum_d Q~[l][d]*Ksum[d] + eps)
// MFMA. KV staged once per block into LDS as pre-split bf16 hi/lo, transposed
// to [e][k'] with column permutation k'(d) s.t. each B fragment is one aligned
// ds_read_b128, plus (e&3)<<3 XOR swizzle. z stays fully fp32.
// grid: NHTOT*64 blocks, 256 threads (R1 shape: full 32 waves/CU).
// Staging uses float4 loads (4 per thread).
// ---------------------------------------------------------------------------
#define KVSTR 72   // bf16 row stride: 144 B, keeps b128 reads aligned

__global__ __launch_bounds__(256) void k3_out(const float* __restrict__ Qin,
                                              const float* __restrict__ fin,
                                              float* __restrict__ out) {
    const int blk = blockIdx.x;
    const int nh  = blk >> 6;        // 64 L-chunks per nh
    const int lc  = blk & 63;
    const int n = nh >> 3, h = nh & 7;
    const int t = threadIdx.x;
    const int w = t >> 6, lane = t & 63;
    const int g = lane >> 4, r = lane & 15;

    __shared__ __align__(16) short KThi[DD][KVSTR];
    __shared__ __align__(16) short KTlo[DD][KVSTR];
    __shared__ __align__(16) float Ksm[DD];

    const float* fb = fin + (size_t)nh * PART_STRIDE;
    {
        // stage: thread t handles flat elements 16t..16t+15 (d = t>>2 const,
        // e = 16*(t&3) + m) -> four float4 loads, fully coalesced
        const int i0 = t * 16;
        const int d  = i0 >> 6;          // t>>2
        const int e0 = i0 & 63;          // (t&3)*16
        float xs[16];
#pragma unroll
        for (int q = 0; q < 4; ++q) {
            const float4 x4 = *(const float4*)(fb + i0 + 4*q);
            xs[4*q+0] = x4.x; xs[4*q+1] = x4.y; xs[4*q+2] = x4.z; xs[4*q+3] = x4.w;
        }
        // k'(d): bits [d5][d3 d2][d4][d1 d0] (bijection)
        const int colb = (d & 32) | (d & 3) | (((d >> 4) & 1) << 2)
                         | (((d >> 2) & 3) << 3);
#pragma unroll
        for (int m = 0; m < 16; ++m) {
            const int e = e0 + m;
            const int col = colb ^ ((e & 3) << 3);
            const float x = xs[m];
            const uint32_t ux = __float_as_uint(x);
            const float lo = x - __uint_as_float(ux & 0xFFFF0000u);
            KThi[e][col] = (short)(ux >> 16);
            KTlo[e][col] = (short)(__float_as_uint(lo) >> 16);
        }
        if (t < DD) Ksm[t] = fb[KVSZ + t];
    }
    __syncthreads();

    const size_t qrow = (size_t)n * LQ + (size_t)lc * LT + w * 16 + r;
    const float* qp = Qin + qrow * ROWSTRIDE + (size_t)h * DD;

    const f32x4 zero4 = {0.f, 0.f, 0.f, 0.f};
    f32x4 acc[4] = {zero4, zero4, zero4, zero4};
    float z = 0.f;

#pragma unroll
    for (int kst = 0; kst < 2; ++kst) {
        const int kb = kst * 32;
        // A fragment: Q row r of this wave's tile, k = kb + M(i,g) — contiguous
        const float4 qa = *(const float4*)(qp + kb + 4*g);
        const float4 qb = *(const float4*)(qp + kb + 16 + 4*g);
        float qv[8] = {fmap(qa.x), fmap(qa.y), fmap(qa.z), fmap(qa.w),
                       fmap(qb.x), fmap(qb.y), fmap(qb.z), fmap(qb.w)};
        // z partial in full fp32 against fp32 Ksum (same k indices)
        const float4 ka = *(const float4*)&Ksm[kb + 4*g];
        const float4 kc = *(const float4*)&Ksm[kb + 16 + 4*g];
        z += qv[0]*ka.x + qv[1]*ka.y + qv[2]*ka.z + qv[3]*ka.w
           + qv[4]*kc.x + qv[5]*kc.y + qv[6]*kc.z + qv[7]*kc.w;
        bf16x8 ahi, alo;
        split8(qv, ahi, alo);
        const int cswz = 8 * (g ^ (r & 3));   // undo staging swizzle (e&3 == r&3)
#pragma unroll
        for (int nt = 0; nt < 4; ++nt) {
            const int e = nt*16 + r;
            const bf16x8 bh = *(const bf16x8*)&KThi[e][kb + cswz];
            const bf16x8 bl = *(const bf16x8*)&KTlo[e][kb + cswz];
            acc[nt] = __builtin_amdgcn_mfma_f32_16x16x32_bf16(ahi, bh, acc[nt], 0,0,0);
            acc[nt] = __builtin_amdgcn_mfma_f32_16x16x32_bf16(alo, bh, acc[nt], 0,0,0);
            acc[nt] = __builtin_amdgcn_mfma_f32_16x16x32_bf16(ahi, bl, acc[nt], 0,0,0);
        }
    }

    // z: sum over g-groups -> every lane holds full z for its A-row r
    z += __shfl_xor(z, 16);
    z += __shfl_xor(z, 32);

    const size_t obase0 = ((size_t)n * LQ + (size_t)lc * LT + w * 16) * ROWSTRIDE
                          + (size_t)h * DD;
#pragma unroll
    for (int j = 0; j < 4; ++j) {
        // C row = 4g + j; its z lives in lane (4g+j) (lanes 0..15 hold r==lane)
        const float zj = __shfl(z, 4*g + j);
        const float zi = 1.f / (zj + EPSF);
        const size_t ob = obase0 + (size_t)(4*g + j) * ROWSTRIDE;
#pragma unroll
        for (int nt = 0; nt < 4; ++nt)
            out[ob + nt*16 + r] = acc[nt][j] * zi;
    }
}

// ---------------------------------------------------------------------------
extern "C" void kernel_launch(void* const* d_in, const int* in_sizes, int n_in,
                              void* d_out, int out_size, void* d_ws, size_t ws_size,
                              hipStream_t stream) {
    const float* Q = (const float*)d_in[0];
    const float* K = (const float*)d_in[1];
    const float* V = (const float*)d_in[2];
    float* out = (float*)d_out;

    float* ws   = (float*)d_ws;
    float* part = ws;                                        // 512*4160 floats (~8.5 MB)
    float* fin  = ws + (size_t)NHTOT * CH * PART_STRIDE;     // 32*4160 floats

    k1_kv<<<NHTOT * CH, 256, 0, stream>>>(K, V, part);
    k2_reduce<<<(NHTOT * PART_STRIDE + 255) / 256, 256, 0, stream>>>(part, fin);
    k3_out<<<NHTOT * (LQ / LT), 256, 0, stream>>>(Q, fin, out);
}

// Round 8
// 142.385 us; speedup vs baseline: 1.0537x; 1.0179x over previous
//
#include <hip/hip_runtime.h>
#include <stdint.h>

// Problem constants (reference: N=4, L=4096, S=4096, H=8, D=64, fp32 in/out)
#define NB   4
#define LQ   4096
#define SK   4096
#define NHD  8
#define DD   64
#define ROWSTRIDE (NHD * DD)      // 512 floats between consecutive s (or l) rows
#define CH   16                   // S-chunks per (n,h)
#define SROWS (SK / CH)           // 256 rows per chunk
#define KVSZ (DD * DD)            // 4096
#define PART_STRIDE (KVSZ + DD)   // 4160: KV + Ksum
#define NHTOT (NB * NHD)          // 32
#define LT   64                   // L rows per k3 block
#define EPSF 1e-6f

typedef __attribute__((ext_vector_type(8))) short bf16x8;   // 8 bf16 (4 VGPRs)
typedef __attribute__((ext_vector_type(4))) float f32x4;

union FragU { uint32_t u[4]; bf16x8 v; };

__device__ __forceinline__ float fmap(float x) {
    // elu(x) + 1 == x+1 (x>0) else exp(x)
    return x > 0.f ? x + 1.f : __expf(x);
}

// Truncating hi/lo split of 8 f32 into two bf16x8 fragments.
// hi = trunc_bf16(x); lo = trunc_bf16(x - hi). x ~= hi + lo with rel err ~2^-16.
__device__ __forceinline__ void split8(const float* x, bf16x8& hi, bf16x8& lo) {
    FragU H, L;
#pragma unroll
    for (int p = 0; p < 4; ++p) {
        float a = x[2*p], b = x[2*p+1];
        uint32_t ua = __float_as_uint(a), ub = __float_as_uint(b);
        float ra = a - __uint_as_float(ua & 0xFFFF0000u);   // exact residual
        float rb = b - __uint_as_float(ub & 0xFFFF0000u);
        H.u[p] = (ua >> 16) | (ub & 0xFFFF0000u);
        L.u[p] = (__float_as_uint(ra) >> 16) | (__float_as_uint(rb) & 0xFFFF0000u);
    }
    hi = H.v; lo = L.v;
}

// ---------------------------------------------------------------------------
// k1: partial KV[d][e] = sum_s K~[s][d]*V[s][e]  and  Ksum[d] = sum_s K~[s][d]
// MFMA version, no LDS, no barriers. grid: NHTOT*CH blocks, 256 threads.
// Wave w handles m-tiles {2wm,2wm+1} x n-tiles {2wn,2wn+1} of the 64x64 C.
// Fragment source-k bijection M(i,g) = 16*(i>>2) + 4g + (i&3), identical for
// A and B -> result independent of HW k-layout.
// ---------------------------------------------------------------------------
__global__ __launch_bounds__(256) void k1_kv(const float* __restrict__ Kin,
                                             const float* __restrict__ Vin,
                                             float* __restrict__ part) {
    const int blk   = blockIdx.x;
    const int nh    = blk / CH;
    const int chunk = blk % CH;
    const int n = nh / NHD, h = nh % NHD;
    const int t = threadIdx.x;
    const int w = t >> 6, lane = t & 63;
    const int g = lane >> 4, r = lane & 15;
    const int wm = w & 1, wn = w >> 1;

    const size_t base = ((size_t)n * SK + (size_t)chunk * SROWS) * ROWSTRIDE
                        + (size_t)h * DD;

    const f32x4 zero4 = {0.f, 0.f, 0.f, 0.f};
    f32x4 acc[2][2] = {{zero4, zero4}, {zero4, zero4}};
    float ks[2] = {0.f, 0.f};

    for (int s0 = 0; s0 < SROWS; s0 += 32) {
        float xa[2][8], xb[2][8];
#pragma unroll
        for (int i = 0; i < 8; ++i) {
            const int soff = ((i & 4) << 2) + 4 * g + (i & 3);   // M(i,g)
            const size_t rowb = base + (size_t)(s0 + soff) * ROWSTRIDE;
#pragma unroll
            for (int mt = 0; mt < 2; ++mt)
                xa[mt][i] = Kin[rowb + (wm*2 + mt)*16 + r];
#pragma unroll
            for (int nt = 0; nt < 2; ++nt)
                xb[nt][i] = Vin[rowb + (wn*2 + nt)*16 + r];
        }
        bf16x8 ahi[2], alo[2], bhi[2], blo[2];
#pragma unroll
        for (int mt = 0; mt < 2; ++mt) {
#pragma unroll
            for (int i = 0; i < 8; ++i) xa[mt][i] = fmap(xa[mt][i]);
            if (wn == 0) {          // wave-uniform; avoid double-count (2x dup)
#pragma unroll
                for (int i = 0; i < 8; ++i) ks[mt] += xa[mt][i];
            }
            split8(xa[mt], ahi[mt], alo[mt]);
        }
#pragma unroll
        for (int nt = 0; nt < 2; ++nt) split8(xb[nt], bhi[nt], blo[nt]);
#pragma unroll
        for (int mt = 0; mt < 2; ++mt)
#pragma unroll
            for (int nt = 0; nt < 2; ++nt) {
                acc[mt][nt] = __builtin_amdgcn_mfma_f32_16x16x32_bf16(
                                  ahi[mt], bhi[nt], acc[mt][nt], 0, 0, 0);
                acc[mt][nt] = __builtin_amdgcn_mfma_f32_16x16x32_bf16(
                                  alo[mt], bhi[nt], acc[mt][nt], 0, 0, 0);
                acc[mt][nt] = __builtin_amdgcn_mfma_f32_16x16x32_bf16(
                                  ahi[mt], blo[nt], acc[mt][nt], 0, 0, 0);
            }
    }

    float* pb = part + ((size_t)nh * CH + chunk) * PART_STRIDE;
    // C mapping (m89-verified): col = lane&15, row = 4*(lane>>4) + reg
#pragma unroll
    for (int mt = 0; mt < 2; ++mt) {
        const int dbase = (wm*2 + mt)*16 + 4*g;
#pragma unroll
        for (int nt = 0; nt < 2; ++nt) {
            const int e = (wn*2 + nt)*16 + r;
#pragma unroll
            for (int j = 0; j < 4; ++j)
                pb[(dbase + j) * DD + e] = acc[mt][nt][j];
        }
    }
    if (wn == 0) {
#pragma unroll
        for (int mt = 0; mt < 2; ++mt) {
            float v = ks[mt];
            v += __shfl_xor(v, 16);
            v += __shfl_xor(v, 32);
            if (lane < 16) pb[KVSZ + (wm*2 + mt)*16 + lane] = v;
        }
    }
}

// ---------------------------------------------------------------------------
// k2: sum CH partials -> final [nh][4160]
// ---------------------------------------------------------------------------
__global__ __launch_bounds__(256) void k2_reduce(const float* __restrict__ part,
                                                 float* __restrict__ fin) {
    const int idx = blockIdx.x * 256 + threadIdx.x;
    if (idx >= NHTOT * PART_STRIDE) return;
    const int nh = idx / PART_STRIDE;
    const int j  = idx - nh * PART_STRIDE;
    const float* p = part + (size_t)nh * CH * PART_STRIDE + j;
    float s = 0.f;
#pragma unroll
    for (int cix = 0; cix < CH; ++cix) s += p[(size_t)cix * PART_STRIDE];
    fin[idx] = s;
}

// ---------------------------------------------------------------------------
// k3: out[l][e] = (sum_d Q~[l][d]*KV[d][e]) / (sum_d Q~[l][d]*Ksum[d] + eps)
// MFMA version. KV staged once per block into LDS as pre-split bf16 hi/lo,
// transposed to [e][k'] with column permutation k'(d) s.t. each B fragment is
// a single aligned ds_read_b128, plus (e&3)<<3 XOR swizzle for staging writes.
// z stays fully fp32. grid: NHTOT*64 blocks, 256 threads (wave w = 16 l-rows).
// ---------------------------------------------------------------------------
#define KVSTR 72   // bf16 row stride: 144 B, keeps b128 reads aligned

__global__ __launch_bounds__(256) void k3_out(const float* __restrict__ Qin,
                                              const float* __restrict__ fin,
                                              float* __restrict__ out) {
    const int blk = blockIdx.x;
    const int nh  = blk >> 6;
    const int lc  = blk & 63;
    const int n = nh >> 3, h = nh & 7;
    const int t = threadIdx.x;
    const int w = t >> 6, lane = t & 63;
    const int g = lane >> 4, r = lane & 15;

    __shared__ __align__(16) short KThi[DD][KVSTR];
    __shared__ __align__(16) short KTlo[DD][KVSTR];
    __shared__ __align__(16) float Ksm[DD];

    const float* fb = fin + (size_t)nh * PART_STRIDE;
    {
        // stage: lane e = t&63, quarter dq = t>>6 covers d = 16*dq .. 16*dq+15
        const int e  = t & 63;
        const int dq = t >> 6;
#pragma unroll
        for (int dd = 0; dd < 16; ++dd) {
            const int d = dq * 16 + dd;
            const float x = fb[d * DD + e];
            // k'(d): bits [d5][d3 d2][d4][d1 d0]  (bijection), then e-swizzle
            const int col = (((d & 32) | (d & 3) | (((d >> 4) & 1) << 2)
                              | (((d >> 2) & 3) << 3)) ^ ((e & 3) << 3));
            const uint32_t ux = __float_as_uint(x);
            const float lo = x - __uint_as_float(ux & 0xFFFF0000u);
            KThi[e][col] = (short)(ux >> 16);
            KTlo[e][col] = (short)(__float_as_uint(lo) >> 16);
        }
        if (t < DD) Ksm[t] = fb[KVSZ + t];
    }
    __syncthreads();

    const size_t qrow = (size_t)n * LQ + (size_t)lc * LT + w * 16 + r;
    const float* qp = Qin + qrow * ROWSTRIDE + (size_t)h * DD;

    const f32x4 zero4 = {0.f, 0.f, 0.f, 0.f};
    f32x4 acc[4] = {zero4, zero4, zero4, zero4};
    float z = 0.f;

#pragma unroll
    for (int kst = 0; kst < 2; ++kst) {
        const int kb = kst * 32;
        // A fragment: Q row r of this wave's tile, k = kb + M(i,g) — contiguous
        const float4 qa = *(const float4*)(qp + kb + 4*g);
        const float4 qb = *(const float4*)(qp + kb + 16 + 4*g);
        float qv[8] = {fmap(qa.x), fmap(qa.y), fmap(qa.z), fmap(qa.w),
                       fmap(qb.x), fmap(qb.y), fmap(qb.z), fmap(qb.w)};
        // z partial in full fp32 against fp32 Ksum (same k indices)
        const float4 ka = *(const float4*)&Ksm[kb + 4*g];
        const float4 kc = *(const float4*)&Ksm[kb + 16 + 4*g];
        z += qv[0]*ka.x + qv[1]*ka.y + qv[2]*ka.z + qv[3]*ka.w
           + qv[4]*kc.x + qv[5]*kc.y + qv[6]*kc.z + qv[7]*kc.w;
        bf16x8 ahi, alo;
        split8(qv, ahi, alo);
        const int cswz = 8 * (g ^ (r & 3));   // undo staging swizzle (e&3 == r&3)
#pragma unroll
        for (int nt = 0; nt < 4; ++nt) {
            const int e = nt*16 + r;
            const bf16x8 bh = *(const bf16x8*)&KThi[e][kb + cswz];
            const bf16x8 bl = *(const bf16x8*)&KTlo[e][kb + cswz];
            acc[nt] = __builtin_amdgcn_mfma_f32_16x16x32_bf16(ahi, bh, acc[nt], 0,0,0);
            acc[nt] = __builtin_amdgcn_mfma_f32_16x16x32_bf16(alo, bh, acc[nt], 0,0,0);
            acc[nt] = __builtin_amdgcn_mfma_f32_16x16x32_bf16(ahi, bl, acc[nt], 0,0,0);
        }
    }

    // z: sum over g-groups -> every lane holds full z for its A-row r
    z += __shfl_xor(z, 16);
    z += __shfl_xor(z, 32);

    const size_t obase0 = ((size_t)n * LQ + (size_t)lc * LT + w * 16) * ROWSTRIDE
                          + (size_t)h * DD;
#pragma unroll
    for (int j = 0; j < 4; ++j) {
        // C row = 4g + j; its z lives in lane (4g+j) (lanes 0..15 hold r==lane)
        const float zj = __shfl(z, 4*g + j);
        const float zi = 1.f / (zj + EPSF);
        const size_t ob = obase0 + (size_t)(4*g + j) * ROWSTRIDE;
#pragma unroll
        for (int nt = 0; nt < 4; ++nt)
            out[ob + nt*16 + r] = acc[nt][j] * zi;
    }
}

// ---------------------------------------------------------------------------
extern "C" void kernel_launch(void* const* d_in, const int* in_sizes, int n_in,
                              void* d_out, int out_size, void* d_ws, size_t ws_size,
                              hipStream_t stream) {
    const float* Q = (const float*)d_in[0];
    const float* K = (const float*)d_in[1];
    const float* V = (const float*)d_in[2];
    float* out = (float*)d_out;

    float* ws   = (float*)d_ws;
    float* part = ws;                                        // 512*4160 floats
    float* fin  = ws + (size_t)NHTOT * CH * PART_STRIDE;     // 32*4160 floats

    k1_kv<<<NHTOT * CH, 256, 0, stream>>>(K, V, part);
    k2_reduce<<<(NHTOT * PART_STRIDE + 255) / 256, 256, 0, stream>>>(part, fin);
    k3_out<<<NHTOT * (LQ / LT), 256, 0, stream>>>(Q, fin, out);
}